// Round 20
// baseline (229.668 us; speedup 1.0000x reference)
//
#include <hip/hip_runtime.h>

// RGCNConv basis-decomposed, sort-based aggregation + pipelined bf16 MFMA GEMM.
//   Abf = [seg_sum(bf16(x)[src] by (dst,rel)) | bf16(x)]  (bf16, [N][2304])
//   out = Abf @ WcatT^T + bias                            (f32 out)
// R20: R18 intra-tile fragment pipeline RETRY with __launch_bounds__(512,2):
// lifts the 128-VGPR allocator cap (R18's spill) to 256, matching the actual
// 2-waves/SIMD occupancy.  One barrier/K-tile; s=1 frag reads issued under
// s=0 MFMA cluster.  Non-GEMM = R15.

#define N_NODES 20000
#define N_EDGES 640000
#define IN_DIM  256
#define OUT_DIM 800
#define NREL    8
#define NSEG    160000          // N_NODES * NREL
#define KS      2048            // NREL * IN_DIM
#define KTOT    2304            // KS + IN_DIM
#define NPAD    1024
#define NB      625             // NSEG / 256

// GEMM geometry: 448x160 tile, BK=64, 8 waves (4Mx2N, 112x80 each)
#define BM 448
#define BN 160
#define BK 64
#define NKT (KTOT / BK)         // 36
#define MT  45                  // ceil(20000/448)
#define NT  5                   // 800/160, exact
#define NWG (MT * NT)           // 225  (<256 -> one round)
#define ABYTES 57344            // A region: 448 rows x 128B
#define LBUF 77824              // + B region: 160 x 128B = 20480

// fused init kernel block ranges
#define XCAST_B (N_NODES * 64 / 256)          // 5000
#define WCAT_B  ((KTOT / 8) * 4)              // 1152
#define INIT_NWG (NB + XCAST_B + WCAT_B)      // 6777

typedef float f32x4_t __attribute__((ext_vector_type(4)));
typedef short short8_t __attribute__((ext_vector_type(8)));

__device__ __forceinline__ unsigned short f2bf(float f) {
  unsigned u = __float_as_uint(f);
  u += 0x7fffu + ((u >> 16) & 1u);
  return (unsigned short)(u >> 16);
}

__device__ __forceinline__ float bflo(unsigned w) { return __uint_as_float(w << 16); }
__device__ __forceinline__ float bfhi(unsigned w) { return __uint_as_float(w & 0xffff0000u); }

__device__ __forceinline__ void gload16(const void* g, void* l) {
  __builtin_amdgcn_global_load_lds(
      (const __attribute__((address_space(1))) void*)g,
      (__attribute__((address_space(3))) void*)l, 16, 0, 0);
}

// ---------------- fused init: zero cnt+gtotal | xcast(+xg) | build_wcat ----------------
__global__ void init_kernel(const float* __restrict__ x,
                            const float* __restrict__ bases,
                            const float* __restrict__ att,
                            const float* __restrict__ root,
                            int* __restrict__ cnt,
                            unsigned short* __restrict__ abf,
                            unsigned short* __restrict__ wcatT,
                            unsigned short* __restrict__ xg,
                            int* __restrict__ gtotal) {
  const int b = blockIdx.x;
  const int t = threadIdx.x;
  if (b < NB) {
    cnt[b * 256 + t] = 0;
    if (b == 0 && t == 0) *gtotal = 0;
  } else if (b < NB + XCAST_B) {
    const int id = (b - NB) * 256 + t;           // 20000*64
    const int row = id >> 6, lane = id & 63;
    const float4 v = ((const float4*)x)[(size_t)row * 64 + lane];
    union { unsigned short u[4]; uint2 q; } pk;
    pk.u[0] = f2bf(v.x); pk.u[1] = f2bf(v.y);
    pk.u[2] = f2bf(v.z); pk.u[3] = f2bf(v.w);
    *(uint2*)(abf + (size_t)row * KTOT + KS + lane * 4) = pk.q;
    *(uint2*)(xg + (size_t)row * IN_DIM + lane * 4) = pk.q;   // compact gather copy
  } else {
    // wcat: 8 consecutive k's x 256 consecutive n's; lanes over n -> coalesced.
    const int rem = b - NB - XCAST_B;            // 0..1151
    const int kc = rem >> 2, ng = rem & 3;
    const int k0 = kc * 8;
    const int n  = ng * 256 + t;
    if (n >= OUT_DIM) return;                    // GEMM reads only rows < 800
    union { unsigned short u[8]; uint4 q; } pk;
    if (k0 < KS) {
      const int r = k0 >> 8, i0 = k0 & 255;
      float av[8];
      #pragma unroll
      for (int bb = 0; bb < 8; ++bb) av[bb] = att[r * 8 + bb];
      #pragma unroll
      for (int j = 0; j < 8; ++j) {
        float v = 0.f;
        #pragma unroll
        for (int bb = 0; bb < 8; ++bb)
          v += av[bb] * bases[((size_t)bb * IN_DIM + i0 + j) * OUT_DIM + n];
        pk.u[j] = f2bf(v);
      }
    } else {
      #pragma unroll
      for (int j = 0; j < 8; ++j)
        pk.u[j] = f2bf(root[(size_t)(k0 - KS + j) * OUT_DIM + n]);
    }
    *(uint4*)(wcatT + (size_t)n * KTOT + k0) = pk.q;
  }
}

// ---------------- sort pipeline ----------------

// 4 edges/thread, int4 reads.
__global__ void hist_kernel(const int* __restrict__ ei, const int* __restrict__ et,
                            int* __restrict__ cnt) {
  const int e0 = (blockIdx.x * 256 + threadIdx.x) * 4;
  const int4 d = *(const int4*)(ei + N_EDGES + e0);
  const int4 r = *(const int4*)(et + e0);
  atomicAdd(&cnt[d.x * NREL + r.x], 1);
  atomicAdd(&cnt[d.y * NREL + r.y], 1);
  atomicAdd(&cnt[d.z * NREL + r.z], 1);
  atomicAdd(&cnt[d.w * NREL + r.w], 1);
}

// Range allocation: per-block LDS inclusive scan + one atomicAdd block base.
__global__ void alloc_kernel(const int* __restrict__ cnt, int* __restrict__ off,
                             int* __restrict__ cur, int* __restrict__ gtotal) {
  __shared__ int sm[256];
  __shared__ int sbase;
  const int t = threadIdx.x;
  const int g = blockIdx.x * 256 + t;
  const int v = cnt[g];
  sm[t] = v;
  __syncthreads();
  for (int s = 1; s < 256; s <<= 1) {
    const int a = (t >= s) ? sm[t - s] : 0;
    __syncthreads();
    sm[t] += a;
    __syncthreads();
  }
  if (t == 255) sbase = atomicAdd(gtotal, sm[255]);
  __syncthreads();
  const int ex = sm[t] - v + sbase;
  off[g] = ex;
  cur[g] = ex;
}

// 4 edges/thread, int4 reads.
__global__ void reorder_kernel(const int* __restrict__ ei, const int* __restrict__ et,
                               int* __restrict__ cur, int* __restrict__ sorted_src) {
  const int e0 = (blockIdx.x * 256 + threadIdx.x) * 4;
  const int4 s = *(const int4*)(ei + e0);
  const int4 d = *(const int4*)(ei + N_EDGES + e0);
  const int4 r = *(const int4*)(et + e0);
  sorted_src[atomicAdd(&cur[d.x * NREL + r.x], 1)] = s.x;
  sorted_src[atomicAdd(&cur[d.y * NREL + r.y], 1)] = s.y;
  sorted_src[atomicAdd(&cur[d.z * NREL + r.z], 1)] = s.z;
  sorted_src[atomicAdd(&cur[d.w * NREL + r.w], 1)] = s.w;
}

// One wave per DST node: 8 (dst,r) segments sequentially, same 8 f32
// accumulators (static indexing).  Half-wave h loads edge j+h (uint4 x 32
// lanes); 4-edge unroll; shfl_xor(32) combine; lanes 0-31 store row r.
__global__ void aggregate_kernel(const int* __restrict__ cnt, const int* __restrict__ off,
                                 const int* __restrict__ sorted_src,
                                 const unsigned short* __restrict__ xg,
                                 unsigned short* __restrict__ abf) {
  const int dst = __builtin_amdgcn_readfirstlane(blockIdx.x * 4 + (threadIdx.x >> 6));
  const int l = threadIdx.x & 63;
  const int half = l >> 5;
  const int sl = l & 31;
  unsigned short* const orow = abf + (size_t)dst * KTOT + sl * 8;

  #pragma unroll 1
  for (int r = 0; r < 8; ++r) {
    const int ne = cnt[dst * 8 + r];
    const int o  = off[dst * 8 + r];
    float a0 = 0.f, a1 = 0.f, a2 = 0.f, a3 = 0.f;
    float a4 = 0.f, a5 = 0.f, a6 = 0.f, a7 = 0.f;
    int j = 0;
    for (; j + 4 <= ne; j += 4) {                // 2 independent loads in flight
      const int s0 = sorted_src[o + j + half];
      const int s1 = sorted_src[o + j + 2 + half];
      const uint4 u = *(const uint4*)(xg + (size_t)s0 * IN_DIM + sl * 8);
      const uint4 v = *(const uint4*)(xg + (size_t)s1 * IN_DIM + sl * 8);
      a0 += bflo(u.x); a1 += bfhi(u.x); a2 += bflo(u.y); a3 += bfhi(u.y);
      a4 += bflo(u.z); a5 += bfhi(u.z); a6 += bflo(u.w); a7 += bfhi(u.w);
      a0 += bflo(v.x); a1 += bfhi(v.x); a2 += bflo(v.y); a3 += bfhi(v.y);
      a4 += bflo(v.z); a5 += bfhi(v.z); a6 += bflo(v.w); a7 += bfhi(v.w);
    }
    for (; j + 2 <= ne; j += 2) {
      const int s = sorted_src[o + j + half];
      const uint4 u = *(const uint4*)(xg + (size_t)s * IN_DIM + sl * 8);
      a0 += bflo(u.x); a1 += bfhi(u.x); a2 += bflo(u.y); a3 += bfhi(u.y);
      a4 += bflo(u.z); a5 += bfhi(u.z); a6 += bflo(u.w); a7 += bfhi(u.w);
    }
    if (j < ne && half == 0) {                   // odd tail: half 0 only
      const int s = sorted_src[o + j];
      const uint4 u = *(const uint4*)(xg + (size_t)s * IN_DIM + sl * 8);
      a0 += bflo(u.x); a1 += bfhi(u.x); a2 += bflo(u.y); a3 += bfhi(u.y);
      a4 += bflo(u.z); a5 += bfhi(u.z); a6 += bflo(u.w); a7 += bfhi(u.w);
    }
    a0 += __shfl_xor(a0, 32); a1 += __shfl_xor(a1, 32);
    a2 += __shfl_xor(a2, 32); a3 += __shfl_xor(a3, 32);
    a4 += __shfl_xor(a4, 32); a5 += __shfl_xor(a5, 32);
    a6 += __shfl_xor(a6, 32); a7 += __shfl_xor(a7, 32);
    if (half == 0) {
      union { unsigned short u[8]; uint4 q; } pk;
      pk.u[0] = f2bf(a0); pk.u[1] = f2bf(a1); pk.u[2] = f2bf(a2); pk.u[3] = f2bf(a3);
      pk.u[4] = f2bf(a4); pk.u[5] = f2bf(a5); pk.u[6] = f2bf(a6); pk.u[7] = f2bf(a7);
      *(uint4*)(orow + r * IN_DIM) = pk.q;
    }
  }
}

// C[20000][800] = Abf[20000][2304] @ WcatT^T + bias.
// 448x160 tile, BK=64, 8 waves 4Mx2N (112x80, acc[7][5]); double-buffer,
// dist-1; ONE barrier per K-tile, s=1 frag reads issued under s=0 MFMA
// cluster.  launch_bounds(512,2): 2 waves/EU (the actual occupancy) ->
// 256-VGPR cap, room for the 24 pipelined fragments without spill.
__global__ __launch_bounds__(512, 2) void gemm_kernel(
    const unsigned short* __restrict__ abf,
    const unsigned short* __restrict__ wcatT,
    const float* __restrict__ bias, float* __restrict__ out) {
  __shared__ __align__(16) char lds[2 * LBUF];   // 155648 B

  const int lin = blockIdx.x;
  const int q8 = NWG >> 3, r8 = NWG & 7;         // 28, 1
  const int xcd = lin & 7, idx = lin >> 3;
  const int wg = (xcd < r8 ? xcd * (q8 + 1) : r8 * (q8 + 1) + (xcd - r8) * q8) + idx;
  const int row0 = (wg / NT) * BM;
  const int col0 = (wg % NT) * BN;

  const int tid = threadIdx.x;
  const int w = tid >> 6, l = tid & 63;
  const int wm = w >> 1, wn = w & 1;             // wave: rows wm*112, cols wn*80
  const int la = l & 15, lg = l >> 4;
  const int l3 = l >> 3;
  const int sch = (l & 7) ^ l3;                  // pre-swizzled global k-chunk (T2)

  const unsigned short* gA[7];
  #pragma unroll
  for (int i = 0; i < 7; ++i) {
    int ga = row0 + i * 64 + w * 8 + l3;
    ga = (ga < N_NODES) ? ga : (N_NODES - 1);    // clamp: garbage rows never stored
    gA[i] = abf + (size_t)ga * KTOT + sch * 8;
  }
  const int b2row = (w < 4) ? (128 + w * 8 + l3) : ((w - 4) * 8 + l3);
  const unsigned short* gB0 = wcatT + (size_t)(col0 + w * 8 + l3) * KTOT + sch * 8;
  const unsigned short* gB1 = wcatT + (size_t)(col0 + 64 + w * 8 + l3) * KTOT + sch * 8;
  const unsigned short* gB2 = wcatT + (size_t)(col0 + b2row) * KTOT + sch * 8;
  const int dB2 = (w < 4) ? (ABYTES + 16384 + w * 1024) : (ABYTES + (w - 4) * 1024);

  f32x4_t acc[7][5];
  #pragma unroll
  for (int i = 0; i < 7; ++i)
    #pragma unroll
    for (int j = 0; j < 5; ++j)
      acc[i][j] = (f32x4_t)(0.0f);

  auto stageA = [&](int buf, int kt) {
    char* base = lds + buf * LBUF;
    const int ko = kt * BK;
    #pragma unroll
    for (int i = 0; i < 7; ++i)
      gload16(gA[i] + ko, base + i * 8192 + w * 1024);
  };
  auto stageB = [&](int buf, int kt) {
    char* base = lds + buf * LBUF;
    const int ko = kt * BK;
    gload16(gB0 + ko, base + ABYTES + w * 1024);
    gload16(gB1 + ko, base + ABYTES + 8192 + w * 1024);
    gload16(gB2 + ko, base + dB2);
  };

  stageA(0, 0);
  stageB(0, 0);

  const int rb = wm * 112 + la;
  const int cb = wn * 80 + la;

  for (int kt = 0; kt < NKT; ++kt) {
    const int cbuf = kt & 1;
    const int pbuf = cbuf ^ 1;
    const bool pf = (kt + 1) < NKT;
    const char* Ab = lds + cbuf * LBUF;
    const char* Bb = Ab + ABYTES;

    // my 10 loads (issued a full K-tile ago) done; then the SOLE barrier:
    // all waves drained their prev-tile cbuf reads -> pbuf safely writable,
    // and this tile's staging is visible to all.
    asm volatile("s_waitcnt vmcnt(0)" ::: "memory");
    __builtin_amdgcn_sched_barrier(0);
    __builtin_amdgcn_s_barrier();
    __builtin_amdgcn_sched_barrier(0);

    short8_t af[7], bf[5], ag[7], bg[5];

    // ---- s=0 fragment reads ----
    #pragma unroll
    for (int i = 0; i < 7; ++i) {
      const int rr = rb + i * 16;
      af[i] = *(const short8_t*)(Ab + rr * 128 + ((lg << 4) ^ ((rr & 7) << 4)));
    }
    #pragma unroll
    for (int nf = 0; nf < 5; ++nf) {
      const int rr = cb + nf * 16;
      bf[nf] = *(const short8_t*)(Bb + rr * 128 + ((lg << 4) ^ ((rr & 7) << 4)));
    }
    if (pf) stageA(pbuf, kt + 1);                // 7 gloads under s0-read latency
    asm volatile("s_waitcnt lgkmcnt(0)" ::: "memory");
    __builtin_amdgcn_sched_barrier(0);

    // ---- issue s=1 fragment reads (complete under s=0 MFMA cluster) ----
    #pragma unroll
    for (int i = 0; i < 7; ++i) {
      const int rr = rb + i * 16;
      ag[i] = *(const short8_t*)(Ab + rr * 128 + (((4 + lg) << 4) ^ ((rr & 7) << 4)));
    }
    #pragma unroll
    for (int nf = 0; nf < 5; ++nf) {
      const int rr = cb + nf * 16;
      bg[nf] = *(const short8_t*)(Bb + rr * 128 + (((4 + lg) << 4) ^ ((rr & 7) << 4)));
    }
    __builtin_amdgcn_sched_barrier(0);           // pin: reads issued before MFMAs

    __builtin_amdgcn_s_setprio(1);
    #pragma unroll
    for (int f = 0; f < 7; ++f)
      #pragma unroll
      for (int nf = 0; nf < 5; ++nf)
        acc[f][nf] = __builtin_amdgcn_mfma_f32_16x16x32_bf16(af[f], bf[nf], acc[f][nf], 0, 0, 0);
    __builtin_amdgcn_s_setprio(0);

    if (pf) stageB(pbuf, kt + 1);                // 3 gloads between clusters
    asm volatile("s_waitcnt lgkmcnt(0)" ::: "memory");   // s1 reads (already done)
    __builtin_amdgcn_sched_barrier(0);

    __builtin_amdgcn_s_setprio(1);
    #pragma unroll
    for (int f = 0; f < 7; ++f)
      #pragma unroll
      for (int nf = 0; nf < 5; ++nf)
        acc[f][nf] = __builtin_amdgcn_mfma_f32_16x16x32_bf16(ag[f], bg[nf], acc[f][nf], 0, 0, 0);
    __builtin_amdgcn_s_setprio(0);
  }

  #pragma unroll
  for (int nf = 0; nf < 5; ++nf) {
    const int gcol = col0 + wn * 80 + nf * 16 + la;    // always < 800
    const float bv = bias[gcol];
    #pragma unroll
    for (int f = 0; f < 7; ++f) {
      const int gr0 = row0 + wm * 112 + f * 16 + lg * 4;
      #pragma unroll
      for (int j = 0; j < 4; ++j) {
        const int gr = gr0 + j;
        if (gr < N_NODES)
          out[(size_t)gr * OUT_DIM + gcol] = acc[f][nf][j] + bv;
      }
    }
  }
}

extern "C" void kernel_launch(void* const* d_in, const int* in_sizes, int n_in,
                              void* d_out, int out_size, void* d_ws, size_t ws_size,
                              hipStream_t stream) {
  const float* x     = (const float*)d_in[0];
  const int*   ei    = (const int*)d_in[1];
  const int*   et    = (const int*)d_in[2];
  const float* bases = (const float*)d_in[3];
  const float* att   = (const float*)d_in[4];
  const float* root  = (const float*)d_in[5];
  const float* bias  = (const float*)d_in[6];
  float* out = (float*)d_out;

  char* p = (char*)d_ws;
  unsigned short* abf   = (unsigned short*)p;  p += (size_t)N_NODES * KTOT * 2;  // 92,160,000
  unsigned short* wcatT = (unsigned short*)p;  p += (size_t)NPAD * KTOT * 2;     //  4,718,592
  unsigned short* xg    = (unsigned short*)p;  p += (size_t)N_NODES * IN_DIM * 2;// 10,240,000
  int* cnt        = (int*)p;                   p += (size_t)NSEG * 4;
  int* off        = (int*)p;                   p += (size_t)NSEG * 4;
  int* cur        = (int*)p;                   p += (size_t)NSEG * 4;
  int* sorted_src = (int*)p;                   p += (size_t)N_EDGES * 4;
  int* gtotal     = (int*)p;                   p += 4096;

  init_kernel<<<INIT_NWG, 256, 0, stream>>>(x, bases, att, root, cnt, abf, wcatT, xg, gtotal);
  hist_kernel<<<N_EDGES / 1024, 256, 0, stream>>>(ei, et, cnt);
  alloc_kernel<<<NB, 256, 0, stream>>>(cnt, off, cur, gtotal);
  reorder_kernel<<<N_EDGES / 1024, 256, 0, stream>>>(ei, et, cur, sorted_src);
  aggregate_kernel<<<N_NODES / 4, 256, 0, stream>>>(cnt, off, sorted_src, xg, abf);
  gemm_kernel<<<NWG, 512, 0, stream>>>(abf, wcatT, bias, out);
}

// Round 21
// 221.492 us; speedup vs baseline: 1.0369x; 1.0369x over previous
//
#include <hip/hip_runtime.h>

// RGCNConv basis-decomposed, sort-based aggregation + pipelined bf16 MFMA GEMM.
//   Abf = [seg_sum(bf16(x)[src] by (dst,rel)) | bf16(x)]  (bf16, [N][2304])
//   out = Abf @ WcatT^T + bias                            (f32 out)
// R21 FINAL: = R19/R17 (session best, 221.8us reproduced twice).
// GEMM 448x160 one-round, double-buffered, 2 phases/K-tile.  Non-GEMM = R15.

#define N_NODES 20000
#define N_EDGES 640000
#define IN_DIM  256
#define OUT_DIM 800
#define NREL    8
#define NSEG    160000          // N_NODES * NREL
#define KS      2048            // NREL * IN_DIM
#define KTOT    2304            // KS + IN_DIM
#define NPAD    1024
#define NB      625             // NSEG / 256

// GEMM geometry: 448x160 tile, BK=64, 8 waves (4Mx2N, 112x80 each)
#define BM 448
#define BN 160
#define BK 64
#define NKT (KTOT / BK)         // 36
#define MT  45                  // ceil(20000/448)
#define NT  5                   // 800/160, exact
#define NWG (MT * NT)           // 225  (<256 -> one round)
#define ABYTES 57344            // A region: 448 rows x 128B
#define LBUF 77824              // + B region: 160 x 128B = 20480

// fused init kernel block ranges
#define XCAST_B (N_NODES * 64 / 256)          // 5000
#define WCAT_B  ((KTOT / 8) * 4)              // 1152
#define INIT_NWG (NB + XCAST_B + WCAT_B)      // 6777

typedef float f32x4_t __attribute__((ext_vector_type(4)));
typedef short short8_t __attribute__((ext_vector_type(8)));

__device__ __forceinline__ unsigned short f2bf(float f) {
  unsigned u = __float_as_uint(f);
  u += 0x7fffu + ((u >> 16) & 1u);
  return (unsigned short)(u >> 16);
}

__device__ __forceinline__ float bflo(unsigned w) { return __uint_as_float(w << 16); }
__device__ __forceinline__ float bfhi(unsigned w) { return __uint_as_float(w & 0xffff0000u); }

__device__ __forceinline__ void gload16(const void* g, void* l) {
  __builtin_amdgcn_global_load_lds(
      (const __attribute__((address_space(1))) void*)g,
      (__attribute__((address_space(3))) void*)l, 16, 0, 0);
}

// ---------------- fused init: zero cnt+gtotal | xcast(+xg) | build_wcat ----------------
__global__ void init_kernel(const float* __restrict__ x,
                            const float* __restrict__ bases,
                            const float* __restrict__ att,
                            const float* __restrict__ root,
                            int* __restrict__ cnt,
                            unsigned short* __restrict__ abf,
                            unsigned short* __restrict__ wcatT,
                            unsigned short* __restrict__ xg,
                            int* __restrict__ gtotal) {
  const int b = blockIdx.x;
  const int t = threadIdx.x;
  if (b < NB) {
    cnt[b * 256 + t] = 0;
    if (b == 0 && t == 0) *gtotal = 0;
  } else if (b < NB + XCAST_B) {
    const int id = (b - NB) * 256 + t;           // 20000*64
    const int row = id >> 6, lane = id & 63;
    const float4 v = ((const float4*)x)[(size_t)row * 64 + lane];
    union { unsigned short u[4]; uint2 q; } pk;
    pk.u[0] = f2bf(v.x); pk.u[1] = f2bf(v.y);
    pk.u[2] = f2bf(v.z); pk.u[3] = f2bf(v.w);
    *(uint2*)(abf + (size_t)row * KTOT + KS + lane * 4) = pk.q;
    *(uint2*)(xg + (size_t)row * IN_DIM + lane * 4) = pk.q;   // compact gather copy
  } else {
    // wcat: 8 consecutive k's x 256 consecutive n's; lanes over n -> coalesced.
    const int rem = b - NB - XCAST_B;            // 0..1151
    const int kc = rem >> 2, ng = rem & 3;
    const int k0 = kc * 8;
    const int n  = ng * 256 + t;
    if (n >= OUT_DIM) return;                    // GEMM reads only rows < 800
    union { unsigned short u[8]; uint4 q; } pk;
    if (k0 < KS) {
      const int r = k0 >> 8, i0 = k0 & 255;
      float av[8];
      #pragma unroll
      for (int bb = 0; bb < 8; ++bb) av[bb] = att[r * 8 + bb];
      #pragma unroll
      for (int j = 0; j < 8; ++j) {
        float v = 0.f;
        #pragma unroll
        for (int bb = 0; bb < 8; ++bb)
          v += av[bb] * bases[((size_t)bb * IN_DIM + i0 + j) * OUT_DIM + n];
        pk.u[j] = f2bf(v);
      }
    } else {
      #pragma unroll
      for (int j = 0; j < 8; ++j)
        pk.u[j] = f2bf(root[(size_t)(k0 - KS + j) * OUT_DIM + n]);
    }
    *(uint4*)(wcatT + (size_t)n * KTOT + k0) = pk.q;
  }
}

// ---------------- sort pipeline ----------------

// 4 edges/thread, int4 reads.
__global__ void hist_kernel(const int* __restrict__ ei, const int* __restrict__ et,
                            int* __restrict__ cnt) {
  const int e0 = (blockIdx.x * 256 + threadIdx.x) * 4;
  const int4 d = *(const int4*)(ei + N_EDGES + e0);
  const int4 r = *(const int4*)(et + e0);
  atomicAdd(&cnt[d.x * NREL + r.x], 1);
  atomicAdd(&cnt[d.y * NREL + r.y], 1);
  atomicAdd(&cnt[d.z * NREL + r.z], 1);
  atomicAdd(&cnt[d.w * NREL + r.w], 1);
}

// Range allocation: per-block LDS inclusive scan + one atomicAdd block base.
__global__ void alloc_kernel(const int* __restrict__ cnt, int* __restrict__ off,
                             int* __restrict__ cur, int* __restrict__ gtotal) {
  __shared__ int sm[256];
  __shared__ int sbase;
  const int t = threadIdx.x;
  const int g = blockIdx.x * 256 + t;
  const int v = cnt[g];
  sm[t] = v;
  __syncthreads();
  for (int s = 1; s < 256; s <<= 1) {
    const int a = (t >= s) ? sm[t - s] : 0;
    __syncthreads();
    sm[t] += a;
    __syncthreads();
  }
  if (t == 255) sbase = atomicAdd(gtotal, sm[255]);
  __syncthreads();
  const int ex = sm[t] - v + sbase;
  off[g] = ex;
  cur[g] = ex;
}

// 4 edges/thread, int4 reads.
__global__ void reorder_kernel(const int* __restrict__ ei, const int* __restrict__ et,
                               int* __restrict__ cur, int* __restrict__ sorted_src) {
  const int e0 = (blockIdx.x * 256 + threadIdx.x) * 4;
  const int4 s = *(const int4*)(ei + e0);
  const int4 d = *(const int4*)(ei + N_EDGES + e0);
  const int4 r = *(const int4*)(et + e0);
  sorted_src[atomicAdd(&cur[d.x * NREL + r.x], 1)] = s.x;
  sorted_src[atomicAdd(&cur[d.y * NREL + r.y], 1)] = s.y;
  sorted_src[atomicAdd(&cur[d.z * NREL + r.z], 1)] = s.z;
  sorted_src[atomicAdd(&cur[d.w * NREL + r.w], 1)] = s.w;
}

// One wave per DST node: 8 (dst,r) segments sequentially, same 8 f32
// accumulators (static indexing).  Half-wave h loads edge j+h (uint4 x 32
// lanes); 4-edge unroll; shfl_xor(32) combine; lanes 0-31 store row r.
__global__ void aggregate_kernel(const int* __restrict__ cnt, const int* __restrict__ off,
                                 const int* __restrict__ sorted_src,
                                 const unsigned short* __restrict__ xg,
                                 unsigned short* __restrict__ abf) {
  const int dst = __builtin_amdgcn_readfirstlane(blockIdx.x * 4 + (threadIdx.x >> 6));
  const int l = threadIdx.x & 63;
  const int half = l >> 5;
  const int sl = l & 31;
  unsigned short* const orow = abf + (size_t)dst * KTOT + sl * 8;

  #pragma unroll 1
  for (int r = 0; r < 8; ++r) {
    const int ne = cnt[dst * 8 + r];
    const int o  = off[dst * 8 + r];
    float a0 = 0.f, a1 = 0.f, a2 = 0.f, a3 = 0.f;
    float a4 = 0.f, a5 = 0.f, a6 = 0.f, a7 = 0.f;
    int j = 0;
    for (; j + 4 <= ne; j += 4) {                // 2 independent loads in flight
      const int s0 = sorted_src[o + j + half];
      const int s1 = sorted_src[o + j + 2 + half];
      const uint4 u = *(const uint4*)(xg + (size_t)s0 * IN_DIM + sl * 8);
      const uint4 v = *(const uint4*)(xg + (size_t)s1 * IN_DIM + sl * 8);
      a0 += bflo(u.x); a1 += bfhi(u.x); a2 += bflo(u.y); a3 += bfhi(u.y);
      a4 += bflo(u.z); a5 += bfhi(u.z); a6 += bflo(u.w); a7 += bfhi(u.w);
      a0 += bflo(v.x); a1 += bfhi(v.x); a2 += bflo(v.y); a3 += bfhi(v.y);
      a4 += bflo(v.z); a5 += bfhi(v.z); a6 += bflo(v.w); a7 += bfhi(v.w);
    }
    for (; j + 2 <= ne; j += 2) {
      const int s = sorted_src[o + j + half];
      const uint4 u = *(const uint4*)(xg + (size_t)s * IN_DIM + sl * 8);
      a0 += bflo(u.x); a1 += bfhi(u.x); a2 += bflo(u.y); a3 += bfhi(u.y);
      a4 += bflo(u.z); a5 += bfhi(u.z); a6 += bflo(u.w); a7 += bfhi(u.w);
    }
    if (j < ne && half == 0) {                   // odd tail: half 0 only
      const int s = sorted_src[o + j];
      const uint4 u = *(const uint4*)(xg + (size_t)s * IN_DIM + sl * 8);
      a0 += bflo(u.x); a1 += bfhi(u.x); a2 += bflo(u.y); a3 += bfhi(u.y);
      a4 += bflo(u.z); a5 += bfhi(u.z); a6 += bflo(u.w); a7 += bfhi(u.w);
    }
    a0 += __shfl_xor(a0, 32); a1 += __shfl_xor(a1, 32);
    a2 += __shfl_xor(a2, 32); a3 += __shfl_xor(a3, 32);
    a4 += __shfl_xor(a4, 32); a5 += __shfl_xor(a5, 32);
    a6 += __shfl_xor(a6, 32); a7 += __shfl_xor(a7, 32);
    if (half == 0) {
      union { unsigned short u[8]; uint4 q; } pk;
      pk.u[0] = f2bf(a0); pk.u[1] = f2bf(a1); pk.u[2] = f2bf(a2); pk.u[3] = f2bf(a3);
      pk.u[4] = f2bf(a4); pk.u[5] = f2bf(a5); pk.u[6] = f2bf(a6); pk.u[7] = f2bf(a7);
      *(uint4*)(orow + r * IN_DIM) = pk.q;
    }
  }
}

// C[20000][800] = Abf[20000][2304] @ WcatT^T + bias.
// 448x160 tile, BK=64, 8 waves 4Mx2N (112x80, acc[7][5]); 2 phases/K-tile;
// DOUBLE-buffered 152KB LDS, dist-1 prefetch (lead = 1 full K-tile >> HBM
// latency, so top vmcnt(0) is satisfied-on-arrival); 10 gloads/thread/K-tile
// (A:7 phase-A, B:3 phase-B, waves 4-7 dup the half-instr); col-fastest XCD.
__global__ __launch_bounds__(512) void gemm_kernel(
    const unsigned short* __restrict__ abf,
    const unsigned short* __restrict__ wcatT,
    const float* __restrict__ bias, float* __restrict__ out) {
  __shared__ __align__(16) char lds[2 * LBUF];   // 155648 B

  // T1: bijective XCD-chunk swizzle; col-fastest (A row-panel L2-resident).
  const int lin = blockIdx.x;
  const int q8 = NWG >> 3, r8 = NWG & 7;         // 28, 1
  const int xcd = lin & 7, idx = lin >> 3;
  const int wg = (xcd < r8 ? xcd * (q8 + 1) : r8 * (q8 + 1) + (xcd - r8) * q8) + idx;
  const int row0 = (wg / NT) * BM;
  const int col0 = (wg % NT) * BN;

  const int tid = threadIdx.x;
  const int w = tid >> 6, l = tid & 63;
  const int wm = w >> 1, wn = w & 1;             // wave: rows wm*112, cols wn*80
  const int la = l & 15, lg = l >> 4;
  const int l3 = l >> 3;
  const int sch = (l & 7) ^ l3;                  // pre-swizzled global k-chunk (T2)

  // A staging: instr i covers rows i*64 + w*8 + l3 (i=0..6)
  const unsigned short* gA[7];
  #pragma unroll
  for (int i = 0; i < 7; ++i) {
    int ga = row0 + i * 64 + w * 8 + l3;
    ga = (ga < N_NODES) ? ga : (N_NODES - 1);    // clamp: garbage rows never stored
    gA[i] = abf + (size_t)ga * KTOT + sch * 8;
  }
  // B staging: gB0 rows 0-63, gB1 64-127, gB2 128-159 (waves 0-3) / dup 0-31
  // (waves 4-7, same src+dest as wave w-4's gB0 -> idempotent).
  const int b2row = (w < 4) ? (128 + w * 8 + l3) : ((w - 4) * 8 + l3);
  const unsigned short* gB0 = wcatT + (size_t)(col0 + w * 8 + l3) * KTOT + sch * 8;
  const unsigned short* gB1 = wcatT + (size_t)(col0 + 64 + w * 8 + l3) * KTOT + sch * 8;
  const unsigned short* gB2 = wcatT + (size_t)(col0 + b2row) * KTOT + sch * 8;
  const int dB2 = (w < 4) ? (ABYTES + 16384 + w * 1024) : (ABYTES + (w - 4) * 1024);

  f32x4_t acc[7][5];
  #pragma unroll
  for (int i = 0; i < 7; ++i)
    #pragma unroll
    for (int j = 0; j < 5; ++j)
      acc[i][j] = (f32x4_t)(0.0f);

  auto stageA = [&](int buf, int kt) {
    char* base = lds + buf * LBUF;
    const int ko = kt * BK;
    #pragma unroll
    for (int i = 0; i < 7; ++i)
      gload16(gA[i] + ko, base + i * 8192 + w * 1024);
  };
  auto stageB = [&](int buf, int kt) {
    char* base = lds + buf * LBUF;
    const int ko = kt * BK;
    gload16(gB0 + ko, base + ABYTES + w * 1024);
    gload16(gB1 + ko, base + ABYTES + 8192 + w * 1024);
    gload16(gB2 + ko, base + dB2);
  };

  stageA(0, 0);
  stageB(0, 0);

  for (int kt = 0; kt < NKT; ++kt) {
    const int cbuf = kt & 1;
    const int pbuf = cbuf ^ 1;
    const bool pf = (kt + 1) < NKT;
    const char* Ab = lds + cbuf * LBUF;
    const char* Bb = Ab + ABYTES;

    // kt's 10 loads were issued a full K-tile ago -> drain is cheap.
    asm volatile("s_waitcnt vmcnt(0)" ::: "memory");
    __builtin_amdgcn_sched_barrier(0);
    __builtin_amdgcn_s_barrier();                // staging visible, prev reads done

    short8_t af0, af1, af2, af3, af4, af5, af6, bfv[5];

    // ---- phase A: s=0, 7 af + 5 bf -> 35 MFMA ----
    {
      const int rb = wm * 112 + la;
      af0 = *(const short8_t*)(Ab + (rb      ) * 128 + ((lg << 4) ^ (((rb      ) & 7) << 4)));
      af1 = *(const short8_t*)(Ab + (rb +  16) * 128 + ((lg << 4) ^ (((rb +  16) & 7) << 4)));
      af2 = *(const short8_t*)(Ab + (rb +  32) * 128 + ((lg << 4) ^ (((rb +  32) & 7) << 4)));
      af3 = *(const short8_t*)(Ab + (rb +  48) * 128 + ((lg << 4) ^ (((rb +  48) & 7) << 4)));
      af4 = *(const short8_t*)(Ab + (rb +  64) * 128 + ((lg << 4) ^ (((rb +  64) & 7) << 4)));
      af5 = *(const short8_t*)(Ab + (rb +  80) * 128 + ((lg << 4) ^ (((rb +  80) & 7) << 4)));
      af6 = *(const short8_t*)(Ab + (rb +  96) * 128 + ((lg << 4) ^ (((rb +  96) & 7) << 4)));
      #pragma unroll
      for (int nf = 0; nf < 5; ++nf) {
        const int rr = wn * 80 + nf * 16 + la;
        bfv[nf] = *(const short8_t*)(Bb + rr * 128 + ((lg << 4) ^ ((rr & 7) << 4)));
      }
      if (pf) stageA(pbuf, kt + 1);
      __builtin_amdgcn_s_barrier();
      asm volatile("s_waitcnt lgkmcnt(0)" ::: "memory");
      __builtin_amdgcn_sched_barrier(0);
      __builtin_amdgcn_s_setprio(1);
      #pragma unroll
      for (int nf = 0; nf < 5; ++nf)
        acc[0][nf] = __builtin_amdgcn_mfma_f32_16x16x32_bf16(af0, bfv[nf], acc[0][nf], 0, 0, 0);
      #pragma unroll
      for (int nf = 0; nf < 5; ++nf)
        acc[1][nf] = __builtin_amdgcn_mfma_f32_16x16x32_bf16(af1, bfv[nf], acc[1][nf], 0, 0, 0);
      #pragma unroll
      for (int nf = 0; nf < 5; ++nf)
        acc[2][nf] = __builtin_amdgcn_mfma_f32_16x16x32_bf16(af2, bfv[nf], acc[2][nf], 0, 0, 0);
      #pragma unroll
      for (int nf = 0; nf < 5; ++nf)
        acc[3][nf] = __builtin_amdgcn_mfma_f32_16x16x32_bf16(af3, bfv[nf], acc[3][nf], 0, 0, 0);
      #pragma unroll
      for (int nf = 0; nf < 5; ++nf)
        acc[4][nf] = __builtin_amdgcn_mfma_f32_16x16x32_bf16(af4, bfv[nf], acc[4][nf], 0, 0, 0);
      #pragma unroll
      for (int nf = 0; nf < 5; ++nf)
        acc[5][nf] = __builtin_amdgcn_mfma_f32_16x16x32_bf16(af5, bfv[nf], acc[5][nf], 0, 0, 0);
      #pragma unroll
      for (int nf = 0; nf < 5; ++nf)
        acc[6][nf] = __builtin_amdgcn_mfma_f32_16x16x32_bf16(af6, bfv[nf], acc[6][nf], 0, 0, 0);
      __builtin_amdgcn_s_setprio(0);
      __builtin_amdgcn_s_barrier();
    }
    // ---- phase B: s=1 ----
    {
      const int rb = wm * 112 + la;
      af0 = *(const short8_t*)(Ab + (rb      ) * 128 + (((4 + lg) << 4) ^ (((rb      ) & 7) << 4)));
      af1 = *(const short8_t*)(Ab + (rb +  16) * 128 + (((4 + lg) << 4) ^ (((rb +  16) & 7) << 4)));
      af2 = *(const short8_t*)(Ab + (rb +  32) * 128 + (((4 + lg) << 4) ^ (((rb +  32) & 7) << 4)));
      af3 = *(const short8_t*)(Ab + (rb +  48) * 128 + (((4 + lg) << 4) ^ (((rb +  48) & 7) << 4)));
      af4 = *(const short8_t*)(Ab + (rb +  64) * 128 + (((4 + lg) << 4) ^ (((rb +  64) & 7) << 4)));
      af5 = *(const short8_t*)(Ab + (rb +  80) * 128 + (((4 + lg) << 4) ^ (((rb +  80) & 7) << 4)));
      af6 = *(const short8_t*)(Ab + (rb +  96) * 128 + (((4 + lg) << 4) ^ (((rb +  96) & 7) << 4)));
      #pragma unroll
      for (int nf = 0; nf < 5; ++nf) {
        const int rr = wn * 80 + nf * 16 + la;
        bfv[nf] = *(const short8_t*)(Bb + rr * 128 + (((4 + lg) << 4) ^ ((rr & 7) << 4)));
      }
      if (pf) stageB(pbuf, kt + 1);
      __builtin_amdgcn_s_barrier();
      asm volatile("s_waitcnt lgkmcnt(0)" ::: "memory");
      __builtin_amdgcn_sched_barrier(0);
      __builtin_amdgcn_s_setprio(1);
      #pragma unroll
      for (int nf = 0; nf < 5; ++nf)
        acc[0][nf] = __builtin_amdgcn_mfma_f32_16x16x32_bf16(af0, bfv[nf], acc[0][nf], 0, 0, 0);
      #pragma unroll
      for (int nf = 0; nf < 5; ++nf)
        acc[1][nf] = __builtin_amdgcn_mfma_f32_16x16x32_bf16(af1, bfv[nf], acc[1][nf], 0, 0, 0);
      #pragma unroll
      for (int nf = 0; nf < 5; ++nf)
        acc[2][nf] = __builtin_amdgcn_mfma_f32_16x16x32_bf16(af2, bfv[nf], acc[2][nf], 0, 0, 0);
      #pragma unroll
      for (int nf = 0; nf < 5; ++nf)
        acc[3][nf] = __builtin_amdgcn_mfma_f32_16x16x32_bf16(af3, bfv[nf], acc[3][nf], 0, 0, 0);
      #pragma unroll
      for (int nf = 0; nf < 5; ++nf)
        acc[4][nf] = __builtin_amdgcn_mfma_f32_16x16x32_bf16(af4, bfv[nf], acc[4][nf], 0, 0, 0);
      #pragma unroll
      for (int nf = 0; nf < 5; ++nf)
        acc[5][nf] = __builtin_amdgcn_mfma_f32_16x16x32_bf16(af5, bfv[nf], acc[5][nf], 0, 0, 0);
      #pragma unroll
      for (int nf = 0; nf < 5; ++nf)
        acc[6][nf] = __builtin_amdgcn_mfma_f32_16x16x32_bf16(af6, bfv[nf], acc[6][nf], 0, 0, 0);
      __builtin_amdgcn_s_setprio(0);
      __builtin_amdgcn_s_barrier();
    }
  }

  #pragma unroll
  for (int nf = 0; nf < 5; ++nf) {
    const int gcol = col0 + wn * 80 + nf * 16 + la;    // always < 800
    const float bv = bias[gcol];
    #pragma unroll
    for (int f = 0; f < 7; ++f) {
      const int gr0 = row0 + wm * 112 + f * 16 + lg * 4;
      #pragma unroll
      for (int j = 0; j < 4; ++j) {
        const int gr = gr0 + j;
        if (gr < N_NODES)
          out[(size_t)gr * OUT_DIM + gcol] = acc[f][nf][j] + bv;
      }
    }
  }
}

extern "C" void kernel_launch(void* const* d_in, const int* in_sizes, int n_in,
                              void* d_out, int out_size, void* d_ws, size_t ws_size,
                              hipStream_t stream) {
  const float* x     = (const float*)d_in[0];
  const int*   ei    = (const int*)d_in[1];
  const int*   et    = (const int*)d_in[2];
  const float* bases = (const float*)d_in[3];
  const float* att   = (const float*)d_in[4];
  const float* root  = (const float*)d_in[5];
  const float* bias  = (const float*)d_in[6];
  float* out = (float*)d_out;

  char* p = (char*)d_ws;
  unsigned short* abf   = (unsigned short*)p;  p += (size_t)N_NODES * KTOT * 2;  // 92,160,000
  unsigned short* wcatT = (unsigned short*)p;  p += (size_t)NPAD * KTOT * 2;     //  4,718,592
  unsigned short* xg    = (unsigned short*)p;  p += (size_t)N_NODES * IN_DIM * 2;// 10,240,000
  int* cnt        = (int*)p;                   p += (size_t)NSEG * 4;
  int* off        = (int*)p;                   p += (size_t)NSEG * 4;
  int* cur        = (int*)p;                   p += (size_t)NSEG * 4;
  int* sorted_src = (int*)p;                   p += (size_t)N_EDGES * 4;
  int* gtotal     = (int*)p;                   p += 4096;

  init_kernel<<<INIT_NWG, 256, 0, stream>>>(x, bases, att, root, cnt, abf, wcatT, xg, gtotal);
  hist_kernel<<<N_EDGES / 1024, 256, 0, stream>>>(ei, et, cnt);
  alloc_kernel<<<NB, 256, 0, stream>>>(cnt, off, cur, gtotal);
  reorder_kernel<<<N_EDGES / 1024, 256, 0, stream>>>(ei, et, cur, sorted_src);
  aggregate_kernel<<<N_NODES / 4, 256, 0, stream>>>(cnt, off, sorted_src, xg, abf);
  gemm_kernel<<<NWG, 512, 0, stream>>>(abf, wcatT, bias, out);
}